// Round 2
// baseline (214.229 us; speedup 1.0000x reference)
//
#include <hip/hip_runtime.h>

// ---------------------------------------------------------------------------
// FISTA sparse coding, restructured:
//   L = ||A||_F^2 ; M = A A^T / L (128x128, symmetric, bf16)
//   B = X A^T / L (per-block prologue via MFMA, X read direct from global)
//   iterate 80x:  zpre = z + B - z@M ; x = soft(zpre, 0.2/L) ;
//                 z = x + ((t-1)/t_new)(x - x_old)
// Orientation: D = M . z^T  (A-operand = M rows, B-operand = z^T), so the
// sample dim stays in lane&15 across iterations and z round-trips LDS with
// vector ds_write_b64 / ds_read_b128 only.
// ---------------------------------------------------------------------------

typedef __attribute__((ext_vector_type(8))) __bf16 bf16x8;
typedef __attribute__((ext_vector_type(4))) float f32x4;
typedef __attribute__((ext_vector_type(8))) unsigned short u16x8;
typedef __attribute__((ext_vector_type(4))) unsigned short u16x4;
typedef __attribute__((ext_vector_type(4))) unsigned int u32x4;

#define NITER 80

__device__ __forceinline__ unsigned short f2bf(float f) {
  unsigned int u = __builtin_bit_cast(unsigned int, f);
  u += 0x7FFFu + ((u >> 16) & 1u);   // RNE
  return (unsigned short)(u >> 16);
}

// ---- kernel 1: A(f32) -> A_bf16, plus per-block partial sums of A^2 --------
__global__ __launch_bounds__(256) void prep_a(const float* __restrict__ A,
                                              unsigned short* __restrict__ Abf,
                                              float* __restrict__ partials) {
  int tid = threadIdx.x;
  int idx = (blockIdx.x * 256 + tid) * 4;          // 128 blocks * 1024 f32
  float4 v = *(const float4*)(A + idx);
  u16x4 o;
  o[0] = f2bf(v.x); o[1] = f2bf(v.y); o[2] = f2bf(v.z); o[3] = f2bf(v.w);
  *(u16x4*)(Abf + idx) = o;
  float p = v.x * v.x + v.y * v.y + v.z * v.z + v.w * v.w;
#pragma unroll
  for (int m = 32; m >= 1; m >>= 1) p += __shfl_xor(p, m, 64);
  __shared__ float red[4];
  if ((tid & 63) == 0) red[tid >> 6] = p;
  __syncthreads();
  if (tid == 0) partials[blockIdx.x] = red[0] + red[1] + red[2] + red[3];
}

// ---- kernel 2: M_bf16[k][j] = bf16(dot(A_k, A_j)/L); also store L ----------
__global__ __launch_bounds__(256) void prep_m(const float* __restrict__ A,
                                              const float* __restrict__ partials,
                                              float* __restrict__ Lout,
                                              unsigned short* __restrict__ Mb) {
  int tid = threadIdx.x;
  int k = blockIdx.x;
  int w = tid >> 6, l = tid & 63;
  __shared__ float ak[1024];
  *(float4*)(ak + tid * 4) = *(const float4*)(A + k * 1024 + tid * 4);
  float L = 0.f;
#pragma unroll 1
  for (int i = 0; i < 128; ++i) L += partials[i];  // fixed order: deterministic
  float invL = 1.0f / L;
  if (k == 0 && tid == 0) Lout[0] = L;
  __syncthreads();
#pragma unroll 1
  for (int jj = 0; jj < 32; ++jj) {
    int j = w * 32 + jj;
    const float* aj = A + j * 1024;
    float p = 0.f;
#pragma unroll
    for (int q = 0; q < 4; ++q) {
      float4 x = *(const float4*)(aj + q * 256 + l * 4);
      float4 y = *(const float4*)(ak + q * 256 + l * 4);
      p += x.x * y.x + x.y * y.y + x.z * y.z + x.w * y.w;
    }
#pragma unroll
    for (int m = 32; m >= 1; m >>= 1) p += __shfl_xor(p, m, 64);
    if (l == 0) Mb[k * 128 + j] = f2bf(p * invL);
  }
}

// ---- kernel 3: persistent FISTA, 32 samples per block, 2 waves -------------
// wave w owns j_out in [64w, 64w+64) = 4 tiles of 16.  Per lane (li=l&15,
// g=l>>4):  D/acc/Bn/xr/zr element (t,q,r)  <->  j_out = 64w+16t+4g+r,
// sample = s0 + 16q + li.
// z lives in LDS as bf16 [32 samples][128 codes], 16B chunks XOR-swizzled by
// (sample&15), double-buffered (1 barrier/iter).
__global__ __launch_bounds__(128, 2) void fista(const float* __restrict__ X,
                                                const unsigned short* __restrict__ Abf,
                                                const unsigned short* __restrict__ Mb,
                                                const float* __restrict__ Lptr,
                                                float* __restrict__ out) {
  int tid = threadIdx.x;
  int w = tid >> 6, l = tid & 63;
  int li = l & 15, g = l >> 4;
  int s0 = blockIdx.x * 32;

  __shared__ __align__(16) unsigned short zls[2 * 32 * 128];  // 16 KB

  float L = Lptr[0];
  float invL = 1.0f / L;
  float thr = 0.2f / L;

  // M fragments (A-operand), pinned in registers: M[64w+16t+li][32m+8g .. +8]
  bf16x8 mfr[4][4];
#pragma unroll
  for (int t = 0; t < 4; ++t)
#pragma unroll
    for (int m = 0; m < 4; ++m)
      mfr[t][m] = *(const bf16x8*)(Mb + (64 * w + 16 * t + li) * 128 + 32 * m + 8 * g);

  // ---- prologue: acc[t][q] = Abf_rows . X^T  (K=1024), no LDS needed ----
  f32x4 acc[4][2];
#pragma unroll
  for (int t = 0; t < 4; ++t)
#pragma unroll
    for (int q = 0; q < 2; ++q)
      acc[t][q] = f32x4{0.f, 0.f, 0.f, 0.f};

#pragma unroll 2
  for (int ks = 0; ks < 32; ++ks) {
    bf16x8 xf[2];
#pragma unroll
    for (int q = 0; q < 2; ++q) {
      const float* xp = X + (size_t)(s0 + 16 * q + li) * 1024 + ks * 32 + 8 * g;
      float4 v0 = *(const float4*)(xp);
      float4 v1 = *(const float4*)(xp + 4);
      bf16x8 f;
      f[0] = (__bf16)v0.x; f[1] = (__bf16)v0.y; f[2] = (__bf16)v0.z; f[3] = (__bf16)v0.w;
      f[4] = (__bf16)v1.x; f[5] = (__bf16)v1.y; f[6] = (__bf16)v1.z; f[7] = (__bf16)v1.w;
      xf[q] = f;
    }
#pragma unroll
    for (int t = 0; t < 4; ++t) {
      bf16x8 af = *(const bf16x8*)(Abf + (size_t)(64 * w + 16 * t + li) * 1024 + ks * 32 + 8 * g);
#pragma unroll
      for (int q = 0; q < 2; ++q)
        acc[t][q] = __builtin_amdgcn_mfma_f32_16x16x32_bf16(af, xf[q], acc[t][q], 0, 0, 0);
    }
  }

  f32x4 Bn[4][2], xr[4][2], zr[4][2];
#pragma unroll
  for (int t = 0; t < 4; ++t)
#pragma unroll
    for (int q = 0; q < 2; ++q) {
      Bn[t][q] = -(acc[t][q] * invL);   // Bn = -B  (C-init = Bn - z)
      xr[t][q] = f32x4{0.f, 0.f, 0.f, 0.f};
      zr[t][q] = f32x4{0.f, 0.f, 0.f, 0.f};
    }

  // zero z buffer 0 (z0 = 0): 8192 B over 128 threads
#pragma unroll
  for (int i = 0; i < 4; ++i)
    *(u32x4*)(zls + tid * 32 + i * 8) = u32x4{0u, 0u, 0u, 0u};
  __syncthreads();

  // iteration-invariant LDS offsets (ushort units)
  int roff[2][4], woff[4][2];
#pragma unroll
  for (int q = 0; q < 2; ++q)
#pragma unroll
    for (int m = 0; m < 4; ++m)
      roff[q][m] = (16 * q + li) * 128 + (((4 * m + g) ^ li) * 8);
#pragma unroll
  for (int t = 0; t < 4; ++t)
#pragma unroll
    for (int q = 0; q < 2; ++q)
      woff[t][q] = (16 * q + li) * 128 + (((8 * w + 2 * t + (g >> 1)) ^ li) * 8) + (g & 1) * 4;

  float tf = 1.0f;
#pragma unroll 1
  for (int it = 0; it < NITER; ++it) {
    float tn = 0.5f * (1.0f + sqrtf(1.0f + 4.0f * tf * tf));
    float c = (tf - 1.0f) / tn;
    tf = tn;
    float cp = 1.0f + c;
    const unsigned short* rd = zls + (it & 1) * 4096;
    unsigned short* wr = zls + ((it + 1) & 1) * 4096;

#pragma unroll
    for (int q = 0; q < 2; ++q) {
      bf16x8 zf[4];
#pragma unroll
      for (int m = 0; m < 4; ++m)
        zf[m] = *(const bf16x8*)(rd + roff[q][m]);
#pragma unroll
      for (int t = 0; t < 4; ++t) {
        f32x4 d = Bn[t][q] - zr[t][q];          // C = -B - z
        d = __builtin_amdgcn_mfma_f32_16x16x32_bf16(mfr[t][0], zf[0], d, 0, 0, 0);
        d = __builtin_amdgcn_mfma_f32_16x16x32_bf16(mfr[t][1], zf[1], d, 0, 0, 0);
        d = __builtin_amdgcn_mfma_f32_16x16x32_bf16(mfr[t][2], zf[2], d, 0, 0, 0);
        d = __builtin_amdgcn_mfma_f32_16x16x32_bf16(mfr[t][3], zf[3], d, 0, 0, 0);
        // D = z@M - z - B  =>  zpre = -D ;  soft(-d,thr) = clamp(d) - d
        f32x4 xo = xr[t][q], xn, zm;
#pragma unroll
        for (int r = 0; r < 4; ++r) {
          float dd = d[r];
          float cl = fminf(fmaxf(dd, -thr), thr);
          float x1 = cl - dd;
          xn[r] = x1;
          zm[r] = cp * x1 - c * xo[r];
        }
        xr[t][q] = xn;
        zr[t][q] = zm;
        u16x4 pv;
        pv[0] = __builtin_bit_cast(unsigned short, (__bf16)zm[0]);
        pv[1] = __builtin_bit_cast(unsigned short, (__bf16)zm[1]);
        pv[2] = __builtin_bit_cast(unsigned short, (__bf16)zm[2]);
        pv[3] = __builtin_bit_cast(unsigned short, (__bf16)zm[3]);
        *(u16x4*)(wr + woff[t][q]) = pv;        // 8B ds_write_b64
      }
    }
    __syncthreads();
  }

  // epilogue: x -> out, float4 per (t,q)
#pragma unroll
  for (int t = 0; t < 4; ++t)
#pragma unroll
    for (int q = 0; q < 2; ++q)
      *(f32x4*)(out + (size_t)(s0 + 16 * q + li) * 128 + 64 * w + 16 * t + 4 * g) = xr[t][q];
}

extern "C" void kernel_launch(void* const* d_in, const int* in_sizes, int n_in,
                              void* d_out, int out_size, void* d_ws, size_t ws_size,
                              hipStream_t stream) {
  const float* X = (const float*)d_in[0];          // 32768 x 1024 f32
  const float* A = (const float*)d_in[1];          // 128 x 1024 f32
  float* out = (float*)d_out;                      // 32768 x 128 f32

  float* partials      = (float*)d_ws;                                   // 128 f32
  float* Lout          = (float*)((char*)d_ws + 512);                    // 1 f32
  unsigned short* Abf  = (unsigned short*)((char*)d_ws + 528);           // 256 KB
  unsigned short* Mb   = (unsigned short*)((char*)d_ws + 528 + 262144);  // 32 KB

  prep_a<<<128, 256, 0, stream>>>(A, Abf, partials);
  prep_m<<<128, 256, 0, stream>>>(A, partials, Lout, Mb);
  fista<<<1024, 128, 0, stream>>>(X, Abf, Mb, Lout, out);
}